// Round 8
// baseline (55.849 us; speedup 1.0000x reference)
//
#include <hip/hip_runtime.h>
#include <stdint.h>

// Problem: B=1,000,000 rows; IN=64, H=128, OUT=2, 3 heads, per-row routing u in [0,3).
// out[b,:] = Wb[u[b]] @ relu(W1 @ x[b] + b1) + bb[u[b]]
//
// Roofline: mandatory HBM = x(256MB) + u(4MB) + out(8MB) ~ 268MB -> ~43us @ 6.3TB/s.
//
// Journal:
//  R2:  99us. LDS-W1, VGPR=96, no spill. Latency-bound (no overlap within wave).
//  R3: 135us. Reg-prefetch + forced 64-VGPR cap -> partial spill + half-empty machine.
//  R4: 343us. launch_bounds(256,8) -> VGPR 32 -> 225MB spill. Never force-shrink regs.
//  R5: 190us. waves_per_eu(4,4) -> still 64 VGPR, 71MB spill. Attributes don't help.
//  R6:  61us. Per-wave LDS ring (2x4KB slots) + global_load_lds: outstanding loads live
//       in the vmcnt queue, not VGPRs. WIN.
//  R7:  53us. Pair-shared compute (W1 frags read once per pair), stage(p+1) a full
//       compute-phase (~600cyc) before the wait. Effective ~5.0 TB/s (80% of ceiling).
//  R8 (this): quad-tile slots (16KB), 2-wave blocks. (a) stage->wait distance ~1200cyc
//       > 900cyc HBM latency; (b) W1/b1 LDS reads amortized over 4 tiles (56 ops/slot
//       vs 72); (c) skip-branch instead of clamped restage (saves 24MB dead fetch);
//       u via plain global->reg loads (vmcnt-counted, consumed ~1200cyc later).
//       LDS 48.9KB -> 3 blocks/CU = 6 waves/CU, 96KB/CU in flight (>> 9.2KB BW-delay).

typedef float f32x4 __attribute__((ext_vector_type(4)));
typedef int   i32x4 __attribute__((ext_vector_type(4)));
typedef short short8 __attribute__((ext_vector_type(8)));
typedef __bf16 bf16x8 __attribute__((ext_vector_type(8)));

#define GLOBAL_AS __attribute__((address_space(1)))
#define LDS_AS    __attribute__((address_space(3)))

static __device__ __forceinline__ f32x4 mfma16(bf16x8 a, bf16x8 b, f32x4 c) {
    return __builtin_amdgcn_mfma_f32_16x16x32_bf16(a, b, c, 0, 0, 0);
}

// MFMA k-packing: any bijection (gamma=lane>>4, j)->k works if A and B use the same one.
// Trunk (K=32 step s): k = 32s + 8g + j. D: col=lane&15=batch row, row = h-dim 16t+4g+r.
// Head: A2 row = batch row (matches trunk D -> zero cross-lane movement); k-bijection
//   n = 32s + 16*(j>>2) + 4g + (j&3) = exactly the h-dims this lane holds.
//   D2: col=lane&15 = head*2+out combo (<6), row -> batch row base+4g+r.
__global__ __launch_bounds__(128) void coil_fused(
    const float* __restrict__ x,
    const int*   __restrict__ u,    // routing ids, int32 on device
    const float* __restrict__ W1,   // [128][64]
    const float* __restrict__ b1,   // [128]
    const float* __restrict__ Wb,   // [3][2][128]
    const float* __restrict__ bb,   // [3][2]
    float* __restrict__ out,        // [B][2]
    int nSlots, int nWaves)
{
    __shared__ short w1s[128 * 64];   // 16 KB: W1 as bf16, XOR-swizzled rows
    __shared__ float b1s[128];
    __shared__ float xsl[2][4096];    // 32 KB: per-wave quad-tile slot (16KB each)

    const int tid  = threadIdx.x;
    const int lane = tid & 63;
    const int c    = lane & 15;       // MFMA "parallel" index
    const int g    = lane >> 4;       // k-group gamma
    const int wsl  = tid >> 6;        // wave slot within block (0/1)

    // ---- stage W1 into LDS as bf16, swizzled: phys = logical ^ ((row&7)<<4) ----
    for (int qq = tid; qq < 1024; qq += 128) {
        int row = qq >> 3;
        const float* src = W1 + row * 64 + (qq & 7) * 8;
        short8 v;
        #pragma unroll
        for (int j = 0; j < 8; ++j) v[j] = __builtin_bit_cast(short, (__bf16)src[j]);
        int phys = (qq * 16) ^ ((row & 7) << 4);
        *reinterpret_cast<short8*>(reinterpret_cast<char*>(w1s) + phys) = v;
    }
    b1s[tid] = b1[tid];               // tid < 128 always

    // ---- loop-invariant head-weight fragments (16 VGPR) + head bias ----
    const int ko = c;                  // combo = head*2 + out_pos; valid if < 6
    const bool kvalid = (ko < 6);
    bf16x8 B2[4];
    #pragma unroll
    for (int s = 0; s < 4; ++s) {
        #pragma unroll
        for (int j = 0; j < 8; ++j) {
            int n = 32 * s + ((j >> 2) << 4) + 4 * g + (j & 3);
            B2[s][j] = kvalid ? (__bf16)Wb[ko * 128 + n] : (__bf16)0.0f;
        }
    }
    const float bbr = kvalid ? bb[ko] : 0.0f;
    const int khead = ko >> 1, opos = ko & 1;

    __syncthreads();   // only barrier in the kernel

    // ---- per-lane pre-swizzled GLOBAL offsets for x staging (16 chunks of 1KB) ----
    // LDS phys byte P = i*1024 + lane*16 holds x logical byte P ^ (((P>>8)&7)<<4)
    // (XOR touches bits 4-6 only; row = P>>8 unaffected).
    int xoff[16];
    #pragma unroll
    for (int i = 0; i < 16; ++i) {
        int pb = i * 1024 + lane * 16;
        xoff[i] = pb ^ (((pb >> 8) & 7) << 4);
    }

    // ---- x read offsets within a tile (bytes), swizzle-corrected; tile t = +4096*t ----
    const int sw  = (c & 7) << 4;
    const int r00 = (c * 256 + g * 32 +   0) ^ sw;   // s=0, j=0..3
    const int r01 = (c * 256 + g * 32 +  16) ^ sw;   // s=0, j=4..7
    const int r10 = (c * 256 + g * 32 + 128) ^ sw;   // s=1, j=0..3
    const int r11 = (c * 256 + g * 32 + 144) ^ sw;   // s=1, j=4..7

    const char* xb8 = reinterpret_cast<const char*>(x);
    const char* w1b = reinterpret_cast<const char*>(w1s);
    float* slot = &xsl[wsl][0];
    LDS_AS char* dst = (LDS_AS char*)slot;
    const char* sb = reinterpret_cast<const char*>(slot);

    auto stage = [&](int slotIdx) {
        const char* src = xb8 + (size_t)slotIdx * 16384;
        #pragma unroll
        for (int i = 0; i < 16; ++i)
            __builtin_amdgcn_global_load_lds((const GLOBAL_AS void*)(src + xoff[i]),
                                             (LDS_AS void*)(dst + i * 1024), 16, 0, 0);
    };

    // ---- contiguous slot chunk per wave ----
    const int w = blockIdx.x * 2 + wsl;
    const int qv = nSlots / nWaves, rm = nSlots % nWaves;
    int p          = w * qv + (w < rm ? w : rm);
    const int pend = p + qv + (w < rm ? 1 : 0);
    if (p >= pend) return;

    stage(p);

    for (; p < pend; ++p) {
        // routing ids for the 4 tiles (global->reg; vmcnt-counted, used at stores)
        const int rowbase = p * 64 + 4 * g;
        i32x4 uv[4];
        #pragma unroll
        for (int t = 0; t < 4; ++t)
            uv[t] = *reinterpret_cast<const i32x4*>(u + rowbase + 16 * t);

        // ---- read all 4 tiles' x fragments (waits on this slot's in-flight DMA) ----
        f32x4 xf[4][4];
        #pragma unroll
        for (int t = 0; t < 4; ++t) {
            const char* tb = sb + t * 4096;
            xf[t][0] = *reinterpret_cast<const f32x4*>(tb + r00);
            xf[t][1] = *reinterpret_cast<const f32x4*>(tb + r01);
            xf[t][2] = *reinterpret_cast<const f32x4*>(tb + r10);
            xf[t][3] = *reinterpret_cast<const f32x4*>(tb + r11);
        }
        // ensure the ds_reads above retired before the DMA below can overwrite the slot
        asm volatile("s_waitcnt lgkmcnt(0)" ::: "memory");

        // ---- refill slot with next quad (skip on last iteration) ----
        if (p + 1 < pend) stage(p + 1);

        // ---- pack B1 fragments for all 4 tiles ----
        bf16x8 B1a[4], B1b[4];
        #pragma unroll
        for (int t = 0; t < 4; ++t) {
            #pragma unroll
            for (int j = 0; j < 4; ++j) {
                B1a[t][j]     = (__bf16)xf[t][0][j];
                B1a[t][4 + j] = (__bf16)xf[t][1][j];
                B1b[t][j]     = (__bf16)xf[t][2][j];
                B1b[t][4 + j] = (__bf16)xf[t][3][j];
            }
        }

        // ---- fused trunk+head, W1/b1 fragments shared by all 4 tiles ----
        f32x4 oacc[4];
        #pragma unroll
        for (int t = 0; t < 4; ++t) oacc[t] = f32x4{0.f, 0.f, 0.f, 0.f};

        #pragma unroll
        for (int s = 0; s < 4; ++s) {
            const int t0 = 2 * s, t1 = 2 * s + 1;
            f32x4 bia0 = *reinterpret_cast<const f32x4*>(&b1s[16 * t0 + 4 * g]); // bcast
            f32x4 bia1 = *reinterpret_cast<const f32x4*>(&b1s[16 * t1 + 4 * g]);
            const int lo0 = (16 * t0 + c) * 128 + 16 * g;
            const int lo1 = (16 * t1 + c) * 128 + 16 * g;
            bf16x8 A00 = __builtin_bit_cast(bf16x8, *reinterpret_cast<const short8*>(w1b + (lo0 ^ sw)));
            bf16x8 A01 = __builtin_bit_cast(bf16x8, *reinterpret_cast<const short8*>(w1b + ((lo0 + 64) ^ sw)));
            bf16x8 A10 = __builtin_bit_cast(bf16x8, *reinterpret_cast<const short8*>(w1b + (lo1 ^ sw)));
            bf16x8 A11 = __builtin_bit_cast(bf16x8, *reinterpret_cast<const short8*>(w1b + ((lo1 + 64) ^ sw)));
            #pragma unroll
            for (int t = 0; t < 4; ++t) {
                f32x4 h0 = bia0, h1 = bia1;
                h0 = mfma16(A00, B1a[t], h0);
                h1 = mfma16(A10, B1a[t], h1);
                h0 = mfma16(A01, B1b[t], h0);
                h1 = mfma16(A11, B1b[t], h1);
                bf16x8 A2;
                #pragma unroll
                for (int j = 0; j < 4; ++j) {
                    A2[j]     = (__bf16)fmaxf(h0[j], 0.0f);
                    A2[4 + j] = (__bf16)fmaxf(h1[j], 0.0f);
                }
                oacc[t] = mfma16(A2, B2[s], oacc[t]);
            }
        }

        // ---- per-row head select + store (each out element hits exactly 1 lane) ----
        #pragma unroll
        for (int t = 0; t < 4; ++t) {
            const int m0 = p * 64 + t * 16 + 4 * g;
            if (khead == uv[t][0]) out[(m0 + 0) * 2 + opos] = oacc[t][0] + bbr;
            if (khead == uv[t][1]) out[(m0 + 1) * 2 + opos] = oacc[t][1] + bbr;
            if (khead == uv[t][2]) out[(m0 + 2) * 2 + opos] = oacc[t][2] + bbr;
            if (khead == uv[t][3]) out[(m0 + 3) * 2 + opos] = oacc[t][3] + bbr;
        }
    }
}

extern "C" void kernel_launch(void* const* d_in, const int* in_sizes, int n_in,
                              void* d_out, int out_size, void* d_ws, size_t ws_size,
                              hipStream_t stream) {
    const float* x  = (const float*)d_in[0];
    const int*   u  = (const int*)d_in[1];   // integer inputs are int32 on device
    const float* W1 = (const float*)d_in[2];
    const float* b1 = (const float*)d_in[3];
    const float* Wb = (const float*)d_in[4];
    const float* bb = (const float*)d_in[5];
    float* out = (float*)d_out;

    const int B = in_sizes[1];        // u has one element per row
    const int nTiles = B / 16;        // 62,500 (exact)
    const int nSlots = nTiles / 4;    // 15,625 (exact)

    // LDS/block = 48.9KB -> 3 blocks/CU -> 6 waves/CU, each cycling one 16KB
    // quad-tile slot staged one slot ahead. 768 blocks x 2 waves = 1536 waves.
    int blocks = 768;
    int nWaves = blocks * 2;
    if (nWaves > nSlots) { blocks = (nSlots + 1) / 2; nWaves = blocks * 2; }

    hipLaunchKernelGGL(coil_fused, dim3(blocks), dim3(128), 0, stream,
                       x, u, W1, b1, Wb, bb, out, nSlots, nWaves);
}